// Round 7
// baseline (836.975 us; speedup 1.0000x reference)
//
#include <hip/hip_runtime.h>

// CRF forward scan via MFMA, R7 = R5 structure + init-race fix.
// ROOT CAUSE of R5/R6 failures: V(0) one-hot writes (wave 0, slots 0..120)
// raced with the zero-init loop (wave 1 zeroes idx 64..127) -- no barrier
// between them. Chains 8-15 could start all-zero => absorbing dead state
// => -1e30 outputs. Fix: __syncthreads() between zero-init and one-hot.
// Structure: 16 chains/block; step = E(128x128)·V(128x16) via 8 mfma
// 16x16x32 bf16. 16 blocks x 256 threads (4 waves), wave w owns M-tiles
// 2w,2w+1. Per-step raw barrier: s_waitcnt lgkmcnt(0); s_barrier (no vmcnt
// drain -> h prefetch stays in flight). Per-chain power-of-2 rescale with
// exact int log2 accounting folded into exp2(h*log2e - e7).

typedef short bf16x8 __attribute__((ext_vector_type(8)));
typedef float f32x4  __attribute__((ext_vector_type(4)));

static constexpr int SS=1024, TT=128, CH=16, HCH=4;
#define LOG2E 1.44269504089f
#define LN2F  0.69314718056f

static __device__ __forceinline__ unsigned short f2bf(float f){
    unsigned u = __builtin_bit_cast(unsigned, f);
    u += 0x7fffu + ((u>>16)&1u);
    return (unsigned short)(u>>16);
}
static __device__ __forceinline__ float bf2f(unsigned short s){
    return __builtin_bit_cast(float, ((unsigned)s)<<16);
}

__global__ __launch_bounds__(256,1) void crf_mfma3_kernel(
        const float* __restrict__ h, const float* __restrict__ mask,
        const float* __restrict__ trans, float* __restrict__ out)
{
    const int tid  = threadIdx.x;
    const int wave = tid>>6, lane = tid&63;
    const int c = lane&15, g = lane>>4;   // c: chain (B/D col, A row-in-tile), g: k-group
    const int b0 = blockIdx.x*CH;

    __shared__ unsigned short Vb[2][2048];   // slot=((kk*4+g)*16+c)*8+j <-> state kk*32+g*8+j
    __shared__ float maxb[2][16][20];        // [buf][chain][16 partials]
    __shared__ float lenb[16];
    __shared__ float em_m[16][4], em_e[16][4];

    // ---- len per chain (mask rows monotone)
    {
        const int cc = tid>>4, off = tid&15;
        const float* mr = mask + (size_t)(b0+cc)*SS;
        float p = 0.f;
        for (int q=0;q<SS/16;++q) p += mr[off + q*16];
        #pragma unroll
        for (int o=1;o<16;o<<=1) p += __shfl_xor(p,o,64);
        if (off==0) lenb[cc] = p;
    }
    // ---- zero-init both buffers
    for (int idx=tid; idx<2048; idx+=256){ Vb[0][idx] = 0; Vb[1][idx] = 0; }
    maxb[0][tid>>4][tid&15] = 1.0f;
    maxb[1][tid>>4][tid&15] = 1.0f;
    __syncthreads();                         // <<< THE FIX: order zeroing vs one-hot
    if (tid<16) Vb[0][tid*8] = 0x3F80;       // V(0): one-hot 1.0 at state SOS=0
    __syncthreads();

    const int len_c = (int)(lenb[c] + 0.5f);
    int lenmax = 0;
    #pragma unroll
    for (int q=0;q<16;++q){ int L=(int)(lenb[q]+0.5f); lenmax = (L>lenmax)?L:lenmax; }

    // ---- A-frags: E = exp(trans), row = lane&15 (+tile), k = kk*32+g*8+j
    bf16x8 Af[2][4];
    #pragma unroll
    for (int T=0;T<2;++T){
        const int arow = (2*wave+T)*16 + c;
        #pragma unroll
        for (int kk=0;kk<4;++kk){
            const int kb = kk*32 + g*8;
            float4 e0 = *reinterpret_cast<const float4*>(trans + (size_t)arow*TT + kb);
            float4 e1 = *reinterpret_cast<const float4*>(trans + (size_t)arow*TT + kb + 4);
            bf16x8 a;
            a[0]=(short)f2bf(__expf(e0.x)); a[1]=(short)f2bf(__expf(e0.y));
            a[2]=(short)f2bf(__expf(e0.z)); a[3]=(short)f2bf(__expf(e0.w));
            a[4]=(short)f2bf(__expf(e1.x)); a[5]=(short)f2bf(__expf(e1.y));
            a[6]=(short)f2bf(__expf(e1.z)); a[7]=(short)f2bf(__expf(e1.w));
            Af[T][kk] = a;
        }
    }

    int slotR[4];
    #pragma unroll
    for (int kk=0;kk<4;++kk) slotR[kk] = ((kk*4+g)*16 + c)*8;
    const int r0a = 32*wave + 4*g;           // C/D rows (T=0): r0a..r0a+3
    const int r0b = r0a + 16;                // T=1 rows
    const int slotWA = (((r0a>>5)*4 + ((r0a>>3)&3))*16 + c)*8 + (r0a&7);
    const int slotWB = (((r0b>>5)*4 + ((r0b>>3)&3))*16 + c)*8 + (r0b&7);
    const float* hpA = h + ((size_t)(b0+c)*SS)*TT + r0a;
    const float* hpB = h + ((size_t)(b0+c)*SS)*TT + r0b;

    uint2 svA = make_uint2((wave==0&&g==0)?0x3F80u:0u, 0u);
    uint2 svB = make_uint2(0u,0u);
    float pmxA = (wave==0&&g==0)?1.0f:0.0f, pmxB = 0.0f;
    int   kc = 0;

    auto load_chunk = [&](float4 (*buf)[2], int tbase){
        #pragma unroll
        for (int k=0;k<HCH;++k){
            int t = tbase+k; t = (t<SS)?t:(SS-1);
            buf[k][0] = *reinterpret_cast<const float4*>(hpA + (size_t)t*TT);
            buf[k][1] = *reinterpret_cast<const float4*>(hpB + (size_t)t*TT);
        }
    };

    auto step = [&](const float4* hk, int t){
        const int rb = t&1, wb = rb^1;
        bf16x8 Bf[4];
        #pragma unroll
        for (int kk=0;kk<4;++kk)
            Bf[kk] = *reinterpret_cast<const bf16x8*>(&Vb[rb][slotR[kk]]);
        const float4 m0 = *reinterpret_cast<const float4*>(&maxb[rb][c][0]);
        const float4 m1 = *reinterpret_cast<const float4*>(&maxb[rb][c][4]);
        const float4 m2 = *reinterpret_cast<const float4*>(&maxb[rb][c][8]);
        const float4 m3 = *reinterpret_cast<const float4*>(&maxb[rb][c][12]);
        float w = fmaxf(fmaxf(fmaxf(fmaxf(m0.x,m0.y),fmaxf(m0.z,m0.w)),
                              fmaxf(fmaxf(m1.x,m1.y),fmaxf(m1.z,m1.w))),
                        fmaxf(fmaxf(fmaxf(m2.x,m2.y),fmaxf(m2.z,m2.w)),
                              fmaxf(fmaxf(m3.x,m3.y),fmaxf(m3.z,m3.w))));
        w = fmaxf(w, 1e-35f);
        unsigned wu = __builtin_bit_cast(unsigned, w);
        int e7 = (int)((wu>>23)&0xffu) + (int)((wu>>22)&1u) - 120;
        e7 = (e7 >  30) ?  30 : e7;
        e7 = (e7 < -30) ? -30 : e7;
        const bool live = (t < len_c);
        e7 = live ? e7 : 0;
        const float fsh = (float)(-e7);

        f32x4 acc0 = {0.f,0.f,0.f,0.f}, acc1 = {0.f,0.f,0.f,0.f};
        #pragma unroll
        for (int kk=0;kk<4;++kk){
            acc0 = __builtin_amdgcn_mfma_f32_16x16x32_bf16(Af[0][kk], Bf[kk], acc0, 0,0,0);
            acc1 = __builtin_amdgcn_mfma_f32_16x16x32_bf16(Af[1][kk], Bf[kk], acc1, 0,0,0);
        }
        { // T=0: V' = U * exp2(h*log2e - e7); pmx from ROUNDED values
            unsigned short q0 = f2bf(acc0[0]*exp2f(fmaf(hk[0].x, LOG2E, fsh)));
            unsigned short q1 = f2bf(acc0[1]*exp2f(fmaf(hk[0].y, LOG2E, fsh)));
            unsigned short q2 = f2bf(acc0[2]*exp2f(fmaf(hk[0].z, LOG2E, fsh)));
            unsigned short q3 = f2bf(acc0[3]*exp2f(fmaf(hk[0].w, LOG2E, fsh)));
            uint2 nw = make_uint2((unsigned)q0 | ((unsigned)q1<<16),
                                  (unsigned)q2 | ((unsigned)q3<<16));
            float rmx = fmaxf(fmaxf(bf2f(q0),bf2f(q1)), fmaxf(bf2f(q2),bf2f(q3)));
            svA  = live ? nw : svA;
            pmxA = live ? rmx : pmxA;
            *reinterpret_cast<uint2*>(&Vb[wb][slotWA]) = svA;
        }
        { // T=1
            unsigned short q0 = f2bf(acc1[0]*exp2f(fmaf(hk[1].x, LOG2E, fsh)));
            unsigned short q1 = f2bf(acc1[1]*exp2f(fmaf(hk[1].y, LOG2E, fsh)));
            unsigned short q2 = f2bf(acc1[2]*exp2f(fmaf(hk[1].z, LOG2E, fsh)));
            unsigned short q3 = f2bf(acc1[3]*exp2f(fmaf(hk[1].w, LOG2E, fsh)));
            uint2 nw = make_uint2((unsigned)q0 | ((unsigned)q1<<16),
                                  (unsigned)q2 | ((unsigned)q3<<16));
            float rmx = fmaxf(fmaxf(bf2f(q0),bf2f(q1)), fmaxf(bf2f(q2),bf2f(q3)));
            svB  = live ? nw : svB;
            pmxB = live ? rmx : pmxB;
            *reinterpret_cast<uint2*>(&Vb[wb][slotWB]) = svB;
        }
        kc += e7;
        maxb[wb][c][4*wave+g] = fmaxf(pmxA, pmxB);
        // writes visible before next step's reads; lgkm-only wait so h
        // global loads stay in flight across the barrier
        asm volatile("s_waitcnt lgkmcnt(0)\n\ts_barrier" ::: "memory");
    };

    // ---- main scan: h double-buffered one chunk ahead
    float4 hA[HCH][2], hB[HCH][2];
    load_chunk(hA, 0);
    for (int t0 = 0; t0 < lenmax; t0 += 2*HCH) {
        load_chunk(hB, t0 + HCH);
        #pragma unroll
        for (int k=0;k<HCH;++k) step(hA[k], t0 + k);
        load_chunk(hA, t0 + 2*HCH);
        #pragma unroll
        for (int k=0;k<HCH;++k) step(hB[k], t0 + HCH + k);
    }

    // ---- epilogue: out[b0+c] = logsumexp_j( log V_j + kc*ln2 + trans[EOS=1][j] )
    const float kln = (float)kc * LN2F;
    const float4 teA = *reinterpret_cast<const float4*>(trans + TT + r0a);
    const float4 teB = *reinterpret_cast<const float4*>(trans + TT + r0b);
    float vals[8];
    {
        float va[4] = { bf2f((unsigned short)(svA.x&0xffffu)), bf2f((unsigned short)(svA.x>>16)),
                        bf2f((unsigned short)(svA.y&0xffffu)), bf2f((unsigned short)(svA.y>>16)) };
        float vb[4] = { bf2f((unsigned short)(svB.x&0xffffu)), bf2f((unsigned short)(svB.x>>16)),
                        bf2f((unsigned short)(svB.y&0xffffu)), bf2f((unsigned short)(svB.y>>16)) };
        const float ta[4] = {teA.x, teA.y, teA.z, teA.w};
        const float tb[4] = {teB.x, teB.y, teB.z, teB.w};
        #pragma unroll
        for (int q=0;q<4;++q){
            vals[q]   = (va[q] > 0.f && va[q] < 3.0e38f) ? __logf(va[q]) + kln + ta[q] : -1e30f;
            vals[4+q] = (vb[q] > 0.f && vb[q] < 3.0e38f) ? __logf(vb[q]) + kln + tb[q] : -1e30f;
        }
    }
    float mloc = vals[0];
    #pragma unroll
    for (int q=1;q<8;++q) mloc = fmaxf(mloc, vals[q]);
    float eloc = 0.f;
    #pragma unroll
    for (int q=0;q<8;++q) eloc += __expf(vals[q] - mloc);
    #pragma unroll
    for (int o=16;o<=32;o<<=1){
        float mo = __shfl_xor(mloc, o, 64);
        float eo = __shfl_xor(eloc, o, 64);
        float mn = fmaxf(mloc, mo);
        eloc = eloc*__expf(mloc-mn) + eo*__expf(mo-mn);
        mloc = mn;
    }
    if (g==0){ em_m[c][wave] = mloc; em_e[c][wave] = eloc; }
    __syncthreads();
    if (tid < 16){
        float M = fmaxf(fmaxf(em_m[tid][0],em_m[tid][1]), fmaxf(em_m[tid][2],em_m[tid][3]));
        float E = 0.f;
        #pragma unroll
        for (int q=0;q<4;++q) E += em_e[tid][q]*__expf(em_m[tid][q]-M);
        out[b0+tid] = M + __logf(E);
    }
}

extern "C" void kernel_launch(void* const* d_in, const int* in_sizes, int n_in,
                              void* d_out, int out_size, void* d_ws, size_t ws_size,
                              hipStream_t stream) {
    const float* h     = (const float*)d_in[0];
    const float* mask  = (const float*)d_in[1];
    const float* trans = (const float*)d_in[2];
    float* out         = (float*)d_out;
    crf_mfma3_kernel<<<dim3(256/CH), dim3(256), 0, stream>>>(h, mask, trans, out);
}